// Round 13
// baseline (113.732 us; speedup 1.0000x reference)
//
#include <hip/hip_runtime.h>

#define N_ROWS 16384
#define R_REL  64
#define IN_D   128
#define OUT_D  128
#define BM     32          // rows per tile (16 KB x-LDS)
#define NSLAB  8           // slabs per (relation, col-half); cnt~256 -> ~1 tile each
#define TPB    256
#define MAXL   1024        // LDS row-list capacity (cnt ~ 256 +- 50; 4 KB)

__device__ __forceinline__ float f4c(const float4& v, int i) {
  return i == 0 ? v.x : i == 1 ? v.y : i == 2 ? v.z : v.w;
}

// ---------------------------------------------------------------------------
// k_fused v3 "occupancy": block = (slab, relation r, col-half of 64).
// NO w staging (w = coalesced 16-unique-float4 broadcast loads from L2/L3 —
// the measured-v1 pattern whose VALU cost was only 4 us); x tile 32x128 in
// LDS (XOR-swizzled); rlist via 2-barrier segment scan. LDS ~20.4 KB ->
// 7 blocks/CU resource cap; grid 1024 blocks = 16 waves/CU available
// (4/SIMD, 2.5x the measured 1.6/SIMD of every previous ~40 us variant).
// Thread tile 2 rows x 4 cols; unroll-4 K-loop keeps ~16 w-loads in flight.
// ---------------------------------------------------------------------------
__global__ __launch_bounds__(TPB, 6) void k_fused(const float* __restrict__ x,
                                                  const int* __restrict__ rel,
                                                  const float* __restrict__ w,
                                                  const float* __restrict__ bias,
                                                  float* __restrict__ out) {
  __shared__ __align__(16) float xs[BM * IN_D];    // 16 KB, swizzled 16B chunks
  __shared__ int rlist[MAXL];                      // rows of relation r (4 KB)
  __shared__ int wsum[4];
  const int r    = blockIdx.y;
  const int c0   = blockIdx.z * 64;
  const int slab = blockIdx.x;
  const int t    = threadIdx.x;
  const int wid  = t >> 6, lane = t & 63;
  const int tx   = t & 15, ty = t >> 4;

  // ---- segment scan: thread t owns rel[t*64 .. t*64+64) -> rlist, cntR ----
  const int4* seg = (const int4*)rel + t * 16;
  int c_t = 0;
  #pragma unroll
  for (int i = 0; i < 16; ++i) {
    const int4 v = seg[i];
    c_t += (v.x == r) + (v.y == r) + (v.z == r) + (v.w == r);
  }
  int incl = c_t;
  #pragma unroll
  for (int d = 1; d < 64; d <<= 1) {
    const int u = __shfl_up(incl, d, 64);
    if (lane >= d) incl += u;
  }
  if (lane == 63) wsum[wid] = incl;
  __syncthreads();
  int pos = incl - c_t;
  #pragma unroll
  for (int ww = 0; ww < 4; ++ww) if (ww < wid) pos += wsum[ww];
  const int cntR0 = wsum[0] + wsum[1] + wsum[2] + wsum[3];
  const int cntR = cntR0 < MAXL ? cntR0 : MAXL;
  #pragma unroll
  for (int i = 0; i < 16; ++i) {
    const int4 v = seg[i];
    const int row0 = t * 64 + i * 4;
    if (v.x == r && pos < MAXL) rlist[pos++] = row0;
    if (v.y == r && pos < MAXL) rlist[pos++] = row0 + 1;
    if (v.z == r && pos < MAXL) rlist[pos++] = row0 + 2;
    if (v.w == r && pos < MAXL) rlist[pos++] = row0 + 3;
  }
  __syncthreads();

  // bias slice for this thread's 4 cols (hoisted; L2-hot)
  const float4 bv = *(const float4*)(bias + (size_t)r * OUT_D + c0 + tx * 4);
  const float* wp = w + (size_t)r * (IN_D * OUT_D) + c0 + tx * 4;
  const int rm0 = ty * 2, rm1 = ty * 2 + 1;
  const int sw0 = rm0 & 7, sw1 = rm1 & 7;

  // ---- tile loop (typically exactly 1 tile per block) ----
  for (int tile = slab; tile * BM < cntR; tile += NSLAB) {
    const int t0 = tile * BM;
    const int rows = min(BM, cntR - t0);

    // x-stage: 32 rows x 128 f32; thread: row = t&31, 4 chunks of float4
    {
      const int row = t & 31;
      const int qb = (t >> 5) * 4;               // 0,4,...,28
      if (row < rows) {
        const int g = rlist[t0 + row];
        const float4* src = (const float4*)(x + (size_t)g * IN_D) + qb;
        float4* dst = (float4*)xs + row * 32;
        const int sw = row & 7;
        #pragma unroll
        for (int j = 0; j < 4; ++j) dst[(qb + j) ^ sw] = src[j];
      }
    }
    __syncthreads();

    float4 acc0 = make_float4(0.f, 0.f, 0.f, 0.f);
    float4 acc1 = make_float4(0.f, 0.f, 0.f, 0.f);
    const float4* xr0 = (const float4*)xs + rm0 * 32;
    const float4* xr1 = (const float4*)xs + rm1 * 32;

    #pragma unroll 4
    for (int kc = 0; kc < 32; ++kc) {
      float4 wv[4];
      #pragma unroll
      for (int kk = 0; kk < 4; ++kk)
        wv[kk] = *(const float4*)(wp + (size_t)(kc * 4 + kk) * OUT_D);
      const float4 xv0 = xr0[kc ^ sw0];
      const float4 xv1 = xr1[kc ^ sw1];
      #pragma unroll
      for (int kk = 0; kk < 4; ++kk) {
        const float a0 = f4c(xv0, kk);
        const float a1 = f4c(xv1, kk);
        acc0.x += a0 * wv[kk].x;  acc1.x += a1 * wv[kk].x;
        acc0.y += a0 * wv[kk].y;  acc1.y += a1 * wv[kk].y;
        acc0.z += a0 * wv[kk].z;  acc1.z += a1 * wv[kk].z;
        acc0.w += a0 * wv[kk].w;  acc1.w += a1 * wv[kk].w;
      }
    }

    // epilogue: + bias, scatter 2 rows x 4 cols
    if (rm0 < rows) {
      const int g = rlist[t0 + rm0];
      float4 o;
      o.x = acc0.x + bv.x; o.y = acc0.y + bv.y;
      o.z = acc0.z + bv.z; o.w = acc0.w + bv.w;
      *(float4*)(out + (size_t)g * OUT_D + c0 + tx * 4) = o;
    }
    if (rm1 < rows) {
      const int g = rlist[t0 + rm1];
      float4 o;
      o.x = acc1.x + bv.x; o.y = acc1.y + bv.y;
      o.z = acc1.z + bv.z; o.w = acc1.w + bv.w;
      *(float4*)(out + (size_t)g * OUT_D + c0 + tx * 4) = o;
    }
    __syncthreads();
  }
}

extern "C" void kernel_launch(void* const* d_in, const int* in_sizes, int n_in,
                              void* d_out, int out_size, void* d_ws, size_t ws_size,
                              hipStream_t stream) {
  const float* x    = (const float*)d_in[0];
  const int*   rel  = (const int*)d_in[1];
  const float* w    = (const float*)d_in[2];
  const float* bias = (const float*)d_in[3];
  float* out = (float*)d_out;

  k_fused<<<dim3(NSLAB, R_REL, 2), TPB, 0, stream>>>(x, rel, w, bias, out);
}